// Round 1
// baseline (170.637 us; speedup 1.0000x reference)
//
#include <hip/hip_runtime.h>

#define N_ 4096
#define K_ 64
#define E_ (N_*K_)
#define H_ 256
#define EPS_ 1e-5f

// tanh(x) = 1 - 2/(exp(2x)+1): no overflow/NaN at |x|→inf, v_exp + v_rcp based
__device__ __forceinline__ float ftanh(float x) {
    float e = __expf(2.0f * x);
    return 1.0f - 2.0f * __builtin_amdgcn_rcpf(e + 1.0f);
}

// W01 = W0 @ W1 (4x256), b01 = b0 @ W1 + b1
__global__ __launch_bounds__(256) void prep_kernel(
    const float* __restrict__ W0, const float* __restrict__ b0,
    const float* __restrict__ W1, const float* __restrict__ b1,
    float* __restrict__ W01, float* __restrict__ b01)
{
    int c = threadIdx.x;
    float a0 = 0.f, a1 = 0.f, a2 = 0.f, a3 = 0.f, ab = 0.f;
    for (int h = 0; h < H_; ++h) {
        float w = W1[h * H_ + c];
        a0 = fmaf(W0[0 * H_ + h], w, a0);
        a1 = fmaf(W0[1 * H_ + h], w, a1);
        a2 = fmaf(W0[2 * H_ + h], w, a2);
        a3 = fmaf(W0[3 * H_ + h], w, a3);
        ab = fmaf(b0[h], w, ab);
    }
    W01[c] = a0; W01[H_ + c] = a1; W01[2 * H_ + c] = a2; W01[3 * H_ + c] = a3;
    b01[c] = ab + b1[c];
}

// per-column sum/sumsq of h2 = tanh(T @ W01 + b01) over all E rows
__global__ __launch_bounds__(256) void stats_kernel(
    const float* __restrict__ coor, const float* __restrict__ W01,
    const float* __restrict__ b01, float* __restrict__ sums)
{
    const int c = threadIdx.x;
    const float w0 = W01[c], w1 = W01[H_ + c], w2 = W01[2 * H_ + c], w3 = W01[3 * H_ + c];
    const float bb = b01[c];
    __shared__ float T[256][4];
    const int e0 = blockIdx.x * 256;
    float4 v = reinterpret_cast<const float4*>(coor)[e0 + c];
    T[c][0] = ftanh(v.x); T[c][1] = ftanh(v.y); T[c][2] = ftanh(v.z); T[c][3] = ftanh(v.w);
    __syncthreads();
    float s = 0.f, s2 = 0.f;
    #pragma unroll 8
    for (int r = 0; r < 256; ++r) {
        float h = ftanh(fmaf(T[r][3], w3, fmaf(T[r][2], w2,
                        fmaf(T[r][1], w1, fmaf(T[r][0], w0, bb)))));
        s += h;
        s2 = fmaf(h, h, s2);
    }
    atomicAdd(&sums[c], s);
    atomicAdd(&sums[H_ + c], s2);
}

// fold BN+weights into per-column 8-float record {w0,w1,w2,w3,b01,a,bf,W2c}
__global__ __launch_bounds__(256) void finalize_kernel(
    const float* __restrict__ sums, const float* __restrict__ gamma,
    const float* __restrict__ beta, const float* __restrict__ W2,
    const float* __restrict__ W01, const float* __restrict__ b01,
    float* __restrict__ folded)
{
    int c = threadIdx.x;
    const float inv = 1.0f / (float)E_;
    float mu = sums[c] * inv;
    float var = fmaf(-mu, mu, sums[H_ + c] * inv);
    float rstd = rsqrtf(var + EPS_);
    float a = gamma[c] * rstd;
    float bf = fmaf(-mu, a, beta[c]);
    folded[c * 8 + 0] = W01[c];
    folded[c * 8 + 1] = W01[H_ + c];
    folded[c * 8 + 2] = W01[2 * H_ + c];
    folded[c * 8 + 3] = W01[3 * H_ + c];
    folded[c * 8 + 4] = b01[c];
    folded[c * 8 + 5] = a;
    folded[c * 8 + 6] = bf;
    folded[c * 8 + 7] = W2[c];
}

// thread-per-edge: val (256-col MLP tail) + att, scattered via f32 atomics
__global__ __launch_bounds__(256) void scatter_kernel(
    const float* __restrict__ coor, const int* __restrict__ idx,
    const float* __restrict__ folded,
    const float* __restrict__ Wq, const float* __restrict__ bq,
    const float* __restrict__ Wk, const float* __restrict__ bk,
    const float* __restrict__ b2,
    float* __restrict__ lcker, float* __restrict__ alpha)
{
    const int e = blockIdx.x * 256 + threadIdx.x;
    const int row = idx[e];
    const int col = idx[E_ + e];
    float4 ce = reinterpret_cast<const float4*>(coor)[e];
    // attention: q from row-center element (e = row*K), k from this element
    float4 cc = reinterpret_cast<const float4*>(coor)[row * K_];
    float sx = cc.x + cc.z, sy = cc.y + cc.w;
    float ex = ce.x + ce.z, ey = ce.y + ce.w;
    float att = 0.f;
    #pragma unroll
    for (int j = 0; j < 8; ++j) {
        float qj = fmaf(sy, Wq[8 + j], fmaf(sx, Wq[j], bq[j]));
        float kj = fmaf(ey, Wk[8 + j], fmaf(ex, Wk[j], bk[j]));
        att = fmaf(qj, kj, att);
    }
    att = fabsf(att);
    // val: tanh -> folded 4x256 -> tanh -> BN-folded -> tanh -> dot W2
    float t0 = ftanh(ce.x), t1 = ftanh(ce.y), t2 = ftanh(ce.z), t3 = ftanh(ce.w);
    const float4* F = reinterpret_cast<const float4*>(folded);
    float acc = 0.f;
    #pragma unroll 4
    for (int c = 0; c < H_; ++c) {
        float4 f0 = F[2 * c];
        float4 f1 = F[2 * c + 1];
        float h = ftanh(fmaf(t3, f0.w, fmaf(t2, f0.z,
                        fmaf(t1, f0.y, fmaf(t0, f0.x, f1.x)))));
        h = ftanh(fmaf(h, f1.y, f1.z));
        acc = fmaf(h, f1.w, acc);
    }
    float val = fmaxf(acc + b2[0], 0.f);
    size_t p = (size_t)row * N_ + col;
    atomicAdd(&lcker[p], val);
    atomicAdd(&alpha[p], att);
}

// out = lcker * exp(-alpha*geo) * angle   (dense, float4)
__global__ __launch_bounds__(256) void final_kernel(
    const float* __restrict__ alpha, const float* __restrict__ geo,
    const float* __restrict__ ang, float* __restrict__ out)
{
    int i = blockIdx.x * 256 + threadIdx.x;
    float4 l = reinterpret_cast<float4*>(out)[i];
    float4 a = reinterpret_cast<const float4*>(alpha)[i];
    float4 g = reinterpret_cast<const float4*>(geo)[i];
    float4 r = reinterpret_cast<const float4*>(ang)[i];
    l.x *= __expf(-a.x * g.x) * r.x;
    l.y *= __expf(-a.y * g.y) * r.y;
    l.z *= __expf(-a.z * g.z) * r.z;
    l.w *= __expf(-a.w * g.w) * r.w;
    reinterpret_cast<float4*>(out)[i] = l;
}

extern "C" void kernel_launch(void* const* d_in, const int* in_sizes, int n_in,
                              void* d_out, int out_size, void* d_ws, size_t ws_size,
                              hipStream_t stream)
{
    const float* coor  = (const float*)d_in[1];
    const int*   idx   = (const int*)d_in[2];
    const float* geo   = (const float*)d_in[3];
    const float* ang   = (const float*)d_in[4];
    const float* W0    = (const float*)d_in[5];
    const float* b0    = (const float*)d_in[6];
    const float* W1    = (const float*)d_in[7];
    const float* b1    = (const float*)d_in[8];
    const float* gamma = (const float*)d_in[9];
    const float* beta  = (const float*)d_in[10];
    const float* W2    = (const float*)d_in[11];
    const float* b2    = (const float*)d_in[12];
    const float* Wq    = (const float*)d_in[13];
    const float* bq    = (const float*)d_in[14];
    const float* Wk    = (const float*)d_in[15];
    const float* bk    = (const float*)d_in[16];

    char* ws = (char*)d_ws;
    const size_t NB = (size_t)N_ * N_ * sizeof(float);
    float* alpha  = (float*)ws;                      // N*N f32
    float* sums   = (float*)(ws + NB);               // 512 f32
    float* W01    = (float*)(ws + NB + 2048);        // 1024 f32
    float* b01    = (float*)(ws + NB + 2048 + 4096); // 256 f32
    float* folded = (float*)(ws + NB + 2048 + 4096 + 1024); // 2048 f32

    // zero lcker (accumulated in d_out), alpha, and stats
    hipMemsetAsync(d_out, 0, NB, stream);
    hipMemsetAsync(alpha, 0, NB + 2048, stream);

    prep_kernel<<<1, 256, 0, stream>>>(W0, b0, W1, b1, W01, b01);
    stats_kernel<<<E_ / 256, 256, 0, stream>>>(coor, W01, b01, sums);
    finalize_kernel<<<1, 256, 0, stream>>>(sums, gamma, beta, W2, W01, b01, folded);
    scatter_kernel<<<E_ / 256, 256, 0, stream>>>(coor, idx, folded, Wq, bq, Wk, bk, b2,
                                                 (float*)d_out, alpha);
    final_kernel<<<(N_ * (size_t)N_ / 4) / 256, 256, 0, stream>>>(alpha, geo, ang,
                                                                  (float*)d_out);
}

// Round 2
// 103.983 us; speedup vs baseline: 1.6410x; 1.6410x over previous
//
#include <hip/hip_runtime.h>

#define N_ 4096
#define K_ 64
#define E_ (N_*K_)
#define H_ 256
#define EPS_ 1e-5f

// tanh(x) = 1 - 2/(exp(2x)+1): no overflow/NaN at |x|->inf, v_exp + v_rcp based
__device__ __forceinline__ float ftanh(float x) {
    float e = __expf(2.0f * x);
    return 1.0f - 2.0f * __builtin_amdgcn_rcpf(e + 1.0f);
}

// W01 = W0 @ W1 (4x256), b01 = b0 @ W1 (+ b1 from block 0). 32 blocks x 8 h-rows.
// W01/b01 region must be pre-zeroed (ws memset).
__global__ __launch_bounds__(256) void prep_kernel(
    const float* __restrict__ W0, const float* __restrict__ b0,
    const float* __restrict__ W1, const float* __restrict__ b1,
    float* __restrict__ W01, float* __restrict__ b01)
{
    int c = threadIdx.x;
    int h0 = blockIdx.x * 8;
    float a0 = 0.f, a1 = 0.f, a2 = 0.f, a3 = 0.f, ab = 0.f;
    #pragma unroll
    for (int h = h0; h < h0 + 8; ++h) {
        float w = W1[h * H_ + c];
        a0 = fmaf(W0[0 * H_ + h], w, a0);
        a1 = fmaf(W0[1 * H_ + h], w, a1);
        a2 = fmaf(W0[2 * H_ + h], w, a2);
        a3 = fmaf(W0[3 * H_ + h], w, a3);
        ab = fmaf(b0[h], w, ab);
    }
    if (blockIdx.x == 0) ab += b1[c];
    atomicAdd(&W01[c], a0);
    atomicAdd(&W01[H_ + c], a1);
    atomicAdd(&W01[2 * H_ + c], a2);
    atomicAdd(&W01[3 * H_ + c], a3);
    atomicAdd(&b01[c], ab);
}

// per-column sum/sumsq of h = tanh(T @ W01 + b01) over all E rows
__global__ __launch_bounds__(256) void stats_kernel(
    const float* __restrict__ coor, const float* __restrict__ W01,
    const float* __restrict__ b01, float* __restrict__ sums)
{
    const int c = threadIdx.x;
    const float w0 = W01[c], w1 = W01[H_ + c], w2 = W01[2 * H_ + c], w3 = W01[3 * H_ + c];
    const float bb = b01[c];
    __shared__ float T[256][4];
    const int e0 = blockIdx.x * 256;
    float4 v = reinterpret_cast<const float4*>(coor)[e0 + c];
    T[c][0] = ftanh(v.x); T[c][1] = ftanh(v.y); T[c][2] = ftanh(v.z); T[c][3] = ftanh(v.w);
    __syncthreads();
    float s = 0.f, s2 = 0.f;
    #pragma unroll 8
    for (int r = 0; r < 256; ++r) {
        float h = ftanh(fmaf(T[r][3], w3, fmaf(T[r][2], w2,
                        fmaf(T[r][1], w1, fmaf(T[r][0], w0, bb)))));
        s += h;
        s2 = fmaf(h, h, s2);
    }
    atomicAdd(&sums[c], s);
    atomicAdd(&sums[H_ + c], s2);
}

// fold BN+weights into per-column 8-float record {w0,w1,w2,w3,b01,a,bf,W2c}
__global__ __launch_bounds__(256) void finalize_kernel(
    const float* __restrict__ sums, const float* __restrict__ gamma,
    const float* __restrict__ beta, const float* __restrict__ W2,
    const float* __restrict__ W01, const float* __restrict__ b01,
    float* __restrict__ folded)
{
    int c = threadIdx.x;
    const float inv = 1.0f / (float)E_;
    float mu = sums[c] * inv;
    float var = fmaf(-mu, mu, sums[H_ + c] * inv);
    float rstd = rsqrtf(var + EPS_);
    float a = gamma[c] * rstd;
    float bf = fmaf(-mu, a, beta[c]);
    folded[c * 8 + 0] = W01[c];
    folded[c * 8 + 1] = W01[H_ + c];
    folded[c * 8 + 2] = W01[2 * H_ + c];
    folded[c * 8 + 3] = W01[3 * H_ + c];
    folded[c * 8 + 4] = b01[c];
    folded[c * 8 + 5] = a;
    folded[c * 8 + 6] = bf;
    folded[c * 8 + 7] = W2[c];
}

// Fused edge kernel: one wave = one row (64 edges). Computes val + att per
// edge, dedups duplicate cols within the wave (deterministic lane order),
// leader lane writes out[p] = vsum * exp(-asum*geo[p]) * ang[p] directly.
// All non-edge positions remain at memset zero (lcker==0 there).
__global__ __launch_bounds__(256) void edge_kernel(
    const float* __restrict__ coor, const int* __restrict__ idx,
    const float* __restrict__ folded,
    const float* __restrict__ Wq, const float* __restrict__ bq,
    const float* __restrict__ Wk, const float* __restrict__ bk,
    const float* __restrict__ b2,
    const float* __restrict__ geo, const float* __restrict__ ang,
    float* __restrict__ out)
{
    const int lane = threadIdx.x & 63;
    const int row  = blockIdx.x * 4 + (threadIdx.x >> 6);
    const int e    = row * K_ + lane;
    const int col  = idx[E_ + e];

    float4 ce = reinterpret_cast<const float4*>(coor)[e];
    float ex = ce.x + ce.z, ey = ce.y + ce.w;
    // q comes from the row-center element = lane 0 of this wave
    float sx = __shfl(ex, 0), sy = __shfl(ey, 0);
    float att = 0.f;
    #pragma unroll
    for (int j = 0; j < 8; ++j) {
        float qj = fmaf(sy, Wq[8 + j], fmaf(sx, Wq[j], bq[j]));
        float kj = fmaf(ey, Wk[8 + j], fmaf(ex, Wk[j], bk[j]));
        att = fmaf(qj, kj, att);
    }
    att = fabsf(att);

    // val: tanh -> folded 4x256 -> tanh -> BN-folded -> tanh -> dot W2
    float t0 = ftanh(ce.x), t1 = ftanh(ce.y), t2 = ftanh(ce.z), t3 = ftanh(ce.w);
    const float4* F = reinterpret_cast<const float4*>(folded);
    float acc = 0.f;
    #pragma unroll 4
    for (int c = 0; c < H_; ++c) {
        float4 f0 = F[2 * c];
        float4 f1 = F[2 * c + 1];
        float h = ftanh(fmaf(t3, f0.w, fmaf(t2, f0.z,
                        fmaf(t1, f0.y, fmaf(t0, f0.x, f1.x)))));
        h = ftanh(fmaf(h, f1.y, f1.z));
        acc = fmaf(h, f1.w, acc);
    }
    float val = fmaxf(acc + b2[0], 0.f);

    // intra-wave dedup of duplicate cols, deterministic ascending-lane order
    float vsum = val, asum = att;
    bool leader = true;
    for (int j = 0; j < 64; ++j) {
        int   bc = __shfl(col, j);
        float bv = __shfl(val, j);
        float ba = __shfl(att, j);
        if (bc == col && j != lane) {
            if (j < lane) leader = false;
            else { vsum += bv; asum += ba; }
        }
    }
    if (leader) {
        size_t p = (size_t)row * N_ + col;
        out[p] = vsum * __expf(-asum * geo[p]) * ang[p];
    }
}

extern "C" void kernel_launch(void* const* d_in, const int* in_sizes, int n_in,
                              void* d_out, int out_size, void* d_ws, size_t ws_size,
                              hipStream_t stream)
{
    const float* coor  = (const float*)d_in[1];
    const int*   idx   = (const int*)d_in[2];
    const float* geo   = (const float*)d_in[3];
    const float* ang   = (const float*)d_in[4];
    const float* W0    = (const float*)d_in[5];
    const float* b0    = (const float*)d_in[6];
    const float* W1    = (const float*)d_in[7];
    const float* b1    = (const float*)d_in[8];
    const float* gamma = (const float*)d_in[9];
    const float* beta  = (const float*)d_in[10];
    const float* W2    = (const float*)d_in[11];
    const float* b2    = (const float*)d_in[12];
    const float* Wq    = (const float*)d_in[13];
    const float* bq    = (const float*)d_in[14];
    const float* Wk    = (const float*)d_in[15];
    const float* bk    = (const float*)d_in[16];

    float* ws = (float*)d_ws;
    float* sums   = ws;          // 512 f32
    float* W01    = ws + 512;    // 1024 f32
    float* b01    = ws + 1536;   // 256 f32
    float* folded = ws + 1792;   // 2048 f32

    const size_t NB = (size_t)N_ * N_ * sizeof(float);
    hipMemsetAsync(d_out, 0, NB, stream);          // dense zeros (98.4% of output)
    hipMemsetAsync(ws, 0, 1792 * sizeof(float), stream); // sums + W01 + b01

    prep_kernel<<<32, 256, 0, stream>>>(W0, b0, W1, b1, W01, b01);
    stats_kernel<<<E_ / 256, 256, 0, stream>>>(coor, W01, b01, sums);
    finalize_kernel<<<1, 256, 0, stream>>>(sums, gamma, beta, W2, W01, b01, folded);
    edge_kernel<<<N_ / 4, 256, 0, stream>>>(coor, idx, folded, Wq, bq, Wk, bk, b2,
                                            geo, ang, (float*)d_out);
}